// Round 16
// baseline (3771.879 us; speedup 1.0000x reference)
//
#include <hip/hip_runtime.h>
#include <hip/hip_bf16.h>

// PatchTST encoder: 3 layers of {QKV proj, RealFormer attn, O proj + BN, FFN(GELU) + BN}
// B=32,V=21 -> N=672 seqs; L=128, D=512, H=8, DH=64, F=2048.
// Round 16: r15 (BN folded into weights/epilogues; absmax 0.0625) + the fix for
// r15's regression: __launch_bounds__(512, 8) on gemm_bt pins VGPR <= 64
// (r15's EPI-3 epilogue pushed regalloc to 72, crossing the 64-VGPR granule and
// halving waves/SIMD 8->4 -> occupancy 66%->21%). True pressure is ~36 (r12).

typedef unsigned short u16;
typedef unsigned int u32;
typedef __attribute__((ext_vector_type(8))) short short8;
typedef __attribute__((ext_vector_type(4))) float floatx4;
typedef __attribute__((ext_vector_type(4))) unsigned short ushort4v;

#define DEV static __device__ __forceinline__

DEV u16 f2bf(float f) {
    union { float f; u32 u; } a; a.f = f;
    u32 r = a.u + 0x7FFF + ((a.u >> 16) & 1);   // RNE
    return (u16)(r >> 16);
}
DEV float bf2f(u16 b) {
    union { u32 u; float f; } a; a.u = ((u32)b) << 16; return a.f;
}

DEV void gload16(const void* g, void* l) {
    __builtin_amdgcn_global_load_lds((const __attribute__((address_space(1))) void*)g,
                                     (__attribute__((address_space(3))) void*)l, 16, 0, 0);
}

// ---------------- weight transpose fp32[K][N] -> bf16[N][K], batched over z ------
__global__ void wtrans(const float* __restrict__ W, u16* __restrict__ out, int K, int N,
                       int inStride, int outStride) {
    W += (size_t)blockIdx.z * inStride;
    out += (size_t)blockIdx.z * outStride;
    __shared__ float tile[32][33];
    const int k0 = blockIdx.x * 32, n0 = blockIdx.y * 32;
    const int tx = threadIdx.x & 31, ty = threadIdx.x >> 5;  // 32x8
#pragma unroll
    for (int j = 0; j < 4; ++j) {
        int r = ty + j * 8;
        tile[r][tx] = W[(size_t)(k0 + r) * N + n0 + tx];
    }
    __syncthreads();
#pragma unroll
    for (int j = 0; j < 4; ++j) {
        int r = ty + j * 8;
        out[(size_t)(n0 + r) * K + k0 + tx] = f2bf(tile[tx][r]);
    }
}

__global__ void bias_concat(const float* __restrict__ bq, const float* __restrict__ bk,
                            const float* __restrict__ bv, float* __restrict__ bqkv) {
    int t = blockIdx.x * 256 + threadIdx.x;
    if (t >= 3 * 1536) return;
    int e = t / 1536, c = t % 1536;
    float v = (c < 512) ? bq[e * 512 + c] : (c < 1024) ? bk[e * 512 + c - 512] : bv[e * 512 + c - 1024];
    bqkv[t] = v;
}

__global__ void xconvert(const float* __restrict__ x, u16* __restrict__ hb) {
    size_t i = ((size_t)blockIdx.x * 256 + threadIdx.x) * 8;
    float4 v0 = *(const float4*)&x[i];
    float4 v1 = *(const float4*)&x[i + 4];
    short8 o;
    o[0] = (short)f2bf(v0.x); o[1] = (short)f2bf(v0.y); o[2] = (short)f2bf(v0.z); o[3] = (short)f2bf(v0.w);
    o[4] = (short)f2bf(v1.x); o[5] = (short)f2bf(v1.y); o[6] = (short)f2bf(v1.z); o[7] = (short)f2bf(v1.w);
    *(short8*)&hb[i] = o;
}

// ---------------- BN fold helpers ----------------
// fin layout: fin[c] = t[c], fin[512+c] = s[c]  (BN(x) = s*x + t per channel)
__global__ void zero_stats2(float* raw) { raw[blockIdx.x * 1024 + threadIdx.x] = 0.f; }

__global__ void bn_finalize_st(const float* __restrict__ raw, const float* __restrict__ g,
                               const float* __restrict__ be, float* __restrict__ fin, int M) {
    int c = blockIdx.x * 256 + threadIdx.x;
    if (c >= 512) return;
    float mean = raw[c] / M;
    float var = raw[512 + c] / M - mean * mean;
    float s = rsqrtf(var + 1e-5f) * g[c];
    fin[512 + c] = s;
    fin[c] = be[c] - mean * s;
}

// bias_out[n] = bias_in[n] + sum_k t[k] * Wt[n][k]   (Wt unscaled; K=512)
__global__ void bias_fold(const u16* __restrict__ Wt, const float* __restrict__ bias_in,
                          const float* __restrict__ fin, float* __restrict__ bias_out) {
    __shared__ float tsh[512];
    for (int i = threadIdx.x; i < 512; i += 256) tsh[i] = fin[i];
    __syncthreads();
    int n = blockIdx.x * 256 + threadIdx.x;
    const u16* w = Wt + (size_t)n * 512;
    float acc = bias_in[n];
    for (int k = 0; k < 512; k += 8) {
        short8 wv = *(const short8*)&w[k];
#pragma unroll
        for (int j = 0; j < 8; ++j) acc += tsh[k + j] * bf2f((u16)wv[j]);
    }
    bias_out[n] = acc;
}

// Wt[n][k] *= s[k] in place (K=512; total elements multiple of 2048)
__global__ void weight_scale(u16* __restrict__ Wt, const float* __restrict__ fin) {
    size_t i = ((size_t)blockIdx.x * 256 + threadIdx.x) * 8;
    int k = (int)(i & 511);
    short8 w = *(short8*)&Wt[i];
    short8 o;
#pragma unroll
    for (int j = 0; j < 8; ++j) o[j] = (short)f2bf(bf2f((u16)w[j]) * fin[512 + k + j]);
    *(short8*)&Wt[i] = o;
}

// ---------------- GEMM: C[M,N] = A[M,K](bf16, row-stride lda) @ Bt[N,K]^T + bias ----
// EPI 0: bf16; EPI 1: gelu->bf16; EPI 2: +res -> bf16 (+stats);
// EPI 3: +(s*res+t) -> bf16 (+stats), affine from finRes.
// __launch_bounds__(512, 8): pin VGPR <= 64 (8 waves/SIMD granule).
template <int EPI>
__global__ __launch_bounds__(512, 8)
void gemm_bt(const u16* __restrict__ A, int lda, const u16* __restrict__ Bt,
             const float* __restrict__ bias, const u16* __restrict__ res,
             u16* __restrict__ out, int N, int K, float* __restrict__ stats,
             const float* __restrict__ finRes) {
    __shared__ u16 sA[2][4096];   // [k-half][frag rows 128 x 32]
    __shared__ u16 sB[2][4096];
    const int tid = threadIdx.x;
    const int wave = tid >> 6, lane = tid & 63;
    const int wm = wave >> 2, wn = wave & 3;
    const int m0 = blockIdx.y * 128, n0 = blockIdx.x * 128;
    const int fr = lane & 15, fq = lane >> 4;
    const int srow = lane >> 2, scol = (lane & 3) * 8;

    floatx4 acc[4][2] = {};
    const int NT = K >> 6;

    for (int kt = 0; kt < NT; ++kt) {
        __syncthreads();
        {
            const int ra = wave * 16 + srow;
            const size_t arow = (size_t)(m0 + ra) * lda + kt * 64 + scol;
            const size_t brow = (size_t)(n0 + ra) * (size_t)K + kt * 64 + scol;
#pragma unroll
            for (int kk = 0; kk < 2; ++kk) {
                gload16(A + arow + kk * 32, &sA[kk][wave * 512]);
                gload16(Bt + brow + kk * 32, &sB[kk][wave * 512]);
            }
        }
        __syncthreads();
#pragma unroll
        for (int kk = 0; kk < 2; ++kk) {
            short8 af[4], bfr[2];
#pragma unroll
            for (int m = 0; m < 4; ++m)
                af[m] = *(const short8*)&sA[kk][(wm * 64 + m * 16 + fr) * 32 + fq * 8];
#pragma unroll
            for (int nn = 0; nn < 2; ++nn)
                bfr[nn] = *(const short8*)&sB[kk][(wn * 32 + nn * 16 + fr) * 32 + fq * 8];
#pragma unroll
            for (int m = 0; m < 4; ++m)
#pragma unroll
                for (int nn = 0; nn < 2; ++nn)
                    acc[m][nn] = __builtin_amdgcn_mfma_f32_16x16x32_bf16(af[m], bfr[nn], acc[m][nn], 0, 0, 0);
        }
    }

    // epilogue: C col = lane&15, row = (lane>>4)*4 + reg
    float ssum[2] = { 0.f, 0.f }, sqsum[2] = { 0.f, 0.f };
#pragma unroll
    for (int nn = 0; nn < 2; ++nn) {
        int col = n0 + wn * 32 + nn * 16 + fr;
        float bv = bias[col];
        float rs = 0.f, rt = 0.f;
        if (EPI == 3) { rs = finRes[512 + col]; rt = finRes[col]; }
#pragma unroll
        for (int m = 0; m < 4; ++m) {
            int rowb = m0 + wm * 64 + m * 16 + fq * 4;
#pragma unroll
            for (int r = 0; r < 4; ++r) {
                size_t idx = (size_t)(rowb + r) * N + col;
                float v = acc[m][nn][r] + bv;
                if (EPI == 2) {
                    v += bf2f(res[idx]);
                    ssum[nn] += v; sqsum[nn] += v * v;
                } else if (EPI == 3) {
                    v += rs * bf2f(res[idx]) + rt;
                    ssum[nn] += v; sqsum[nn] += v * v;
                } else if (EPI == 1) {
                    v = 0.5f * v * (1.f + erff(v * 0.70710678118f));
                }
                out[idx] = f2bf(v);
            }
        }
    }
    if (EPI == 2 || EPI == 3) {
#pragma unroll
        for (int nn = 0; nn < 2; ++nn) {
            float s = ssum[nn], q = sqsum[nn];
            s += __shfl_xor(s, 16); s += __shfl_xor(s, 32);
            q += __shfl_xor(q, 16); q += __shfl_xor(q, 32);
            if (fq == 0) {
                int col = n0 + wn * 32 + nn * 16 + fr;
                atomicAdd(&stats[col], s);
                atomicAdd(&stats[512 + col], q);
            }
        }
    }
}

// ---------------- fused attention per (n,h) — r14 version (proven 208us) ----------
template <int HAS_PREV, int STORE_S>
__global__ __launch_bounds__(256)
void attn_kernel(u16* __restrict__ qkv, u16* __restrict__ scores) {
    const int bid = blockIdx.x;           // n*8 + h
    const int n = bid >> 3, h = bid & 7;
    const int tid = threadIdx.x, wave = tid >> 6, lane = tid & 63;
    const int wm = wave >> 1, wn = wave & 1;
    const int fr = lane & 15, fq = lane >> 4;

    __shared__ __align__(16) u16 uni[128 * 136];   // q/k tiles first, then sP [128][136]
    __shared__ __align__(16) u16 sV[64 * 136];     // V^T [64][136]
    __shared__ float sRed[128 * 2];

    u16 (*sQK)[128 * 32] = (u16(*)[128 * 32])uni;  // tiles: q.k0, q.k1, k.k0, k.k1

    {   // stage q,k tiles (global_load_lds), each wave owns one [128][32] tile
        const int t_ = wave;
        const int qk = t_ >> 1, kh = t_ & 1;
        const u16* base = qkv + (size_t)n * 128 * 1536 + qk * 512 + h * 64 + kh * 32 + (lane & 3) * 8;
        u16* dst = &sQK[t_][0];
        const int rr = lane >> 2;
#pragma unroll
        for (int c = 0; c < 8; ++c)
            gload16(base + (size_t)(c * 16 + rr) * 1536, dst + c * 512);
    }
    {   // stage V transposed: sV[dh][m]; global side vectorized (short8)
        const int mrow = tid >> 1;
        const int dh0 = (tid & 1) * 32;
        const u16* vsrc = qkv + (size_t)(n * 128 + mrow) * 1536 + 1024 + h * 64 + dh0;
#pragma unroll
        for (int j = 0; j < 4; ++j) {
            short8 vv = *(const short8*)&vsrc[j * 8];
#pragma unroll
            for (int e2 = 0; e2 < 8; ++e2)
                sV[(dh0 + j * 8 + e2) * 136 + mrow] = (u16)vv[e2];
        }
    }
    __syncthreads();  // [A]

    // QK^T swapped: acc[m][nn] -> S[q-row = wm*64+m*16+fr][k = wn*64+nn*16+fq*4+r]
    floatx4 acc[4][4] = {};
#pragma unroll
    for (int kh = 0; kh < 2; ++kh) {
        short8 a[4], b[4];
#pragma unroll
        for (int m = 0; m < 4; ++m)
            a[m] = *(const short8*)&sQK[kh][(wm * 64 + m * 16 + fr) * 32 + fq * 8];
#pragma unroll
        for (int nn = 0; nn < 4; ++nn)
            b[nn] = *(const short8*)&sQK[2 + kh][(wn * 64 + nn * 16 + fr) * 32 + fq * 8];
#pragma unroll
        for (int m = 0; m < 4; ++m)
#pragma unroll
            for (int nn = 0; nn < 4; ++nn)
                acc[m][nn] = __builtin_amdgcn_mfma_f32_16x16x32_bf16(b[nn], a[m], acc[m][nn], 0, 0, 0);
    }

    // scale, + prev scores, store new scores — fragment layout, short8 I/O
    const size_t tbase = ((size_t)bid * 256 + tid) * 64;
#pragma unroll
    for (int m = 0; m < 4; ++m) {
        short8 lo, hi;
        if (HAS_PREV) {
            lo = *(const short8*)&scores[tbase + m * 16];
            hi = *(const short8*)&scores[tbase + m * 16 + 8];
        }
#pragma unroll
        for (int nn = 0; nn < 4; ++nn)
#pragma unroll
            for (int r = 0; r < 4; ++r) {
                const int e = nn * 4 + r;
                float v = acc[m][nn][r] * 0.125f;
                if (HAS_PREV) v += bf2f((u16)(e < 8 ? lo[e] : hi[e - 8]));
                acc[m][nn][r] = v;
            }
        if (STORE_S) {
            short8 slo, shi;
#pragma unroll
            for (int nn = 0; nn < 4; ++nn)
#pragma unroll
                for (int r = 0; r < 4; ++r) {
                    const int e = nn * 4 + r;
                    u16 bv = f2bf(acc[m][nn][r]);
                    if (e < 8) slo[e] = (short)bv; else shi[e - 8] = (short)bv;
                }
            *(short8*)&scores[tbase + m * 16] = slo;
            *(short8*)&scores[tbase + m * 16 + 8] = shi;
        }
    }

    // row max: in-thread over 16 k-values, shfl over fq (16,32), 2-way wn via LDS
#pragma unroll
    for (int m = 0; m < 4; ++m) {
        const int row = wm * 64 + m * 16 + fr;
        float mx = acc[m][0][0];
#pragma unroll
        for (int nn = 0; nn < 4; ++nn)
#pragma unroll
            for (int r = 0; r < 4; ++r) mx = fmaxf(mx, acc[m][nn][r]);
        mx = fmaxf(mx, __shfl_xor(mx, 16));
        mx = fmaxf(mx, __shfl_xor(mx, 32));
        if (fq == 0) sRed[row * 2 + wn] = mx;
    }
    __syncthreads();  // [B] sQK reads done; max partials ready

    float rmax[4];
#pragma unroll
    for (int m = 0; m < 4; ++m) {
        const int row = wm * 64 + m * 16 + fr;
        rmax[m] = fmaxf(sRed[row * 2], sRed[row * 2 + 1]);
    }
    __syncthreads();  // [C] protect sRed overwrite

    u16* sP = uni;
#pragma unroll
    for (int m = 0; m < 4; ++m) {
        const int row = wm * 64 + m * 16 + fr;
        float sm = 0.f;
#pragma unroll
        for (int nn = 0; nn < 4; ++nn) {
#pragma unroll
            for (int r = 0; r < 4; ++r) {
                float p = __expf(acc[m][nn][r] - rmax[m]);
                acc[m][nn][r] = p;
                sm += p;
            }
        }
        sm += __shfl_xor(sm, 16);
        sm += __shfl_xor(sm, 32);
        if (fq == 0) sRed[row * 2 + wn] = sm;
#pragma unroll
        for (int nn = 0; nn < 4; ++nn) {
            ushort4v pv = { f2bf(acc[m][nn][0]), f2bf(acc[m][nn][1]),
                            f2bf(acc[m][nn][2]), f2bf(acc[m][nn][3]) };
            *(ushort4v*)&sP[row * 136 + wn * 64 + nn * 16 + fq * 4] = pv;
        }
    }
    __syncthreads();  // [D] P + sums ready

    // P @ V swapped: acc2[m][n2] -> ctx[q = wm*64+m*16+fr][dh = wn*32+n2*16+fq*4+r]
    floatx4 acc2[4][2] = {};
#pragma unroll
    for (int k0 = 0; k0 < 128; k0 += 32) {
        short8 a[4], b[2];
#pragma unroll
        for (int m = 0; m < 4; ++m)
            a[m] = *(const short8*)&sP[(wm * 64 + m * 16 + fr) * 136 + k0 + fq * 8];
#pragma unroll
        for (int n2 = 0; n2 < 2; ++n2)
            b[n2] = *(const short8*)&sV[(wn * 32 + n2 * 16 + fr) * 136 + k0 + fq * 8];
#pragma unroll
        for (int m = 0; m < 4; ++m)
#pragma unroll
            for (int n2 = 0; n2 < 2; ++n2)
                acc2[m][n2] = __builtin_amdgcn_mfma_f32_16x16x32_bf16(b[n2], a[m], acc2[m][n2], 0, 0, 0);
    }

#pragma unroll
    for (int m = 0; m < 4; ++m) {
        const int row = wm * 64 + m * 16 + fr;
        const float inv = 1.f / (sRed[row * 2] + sRed[row * 2 + 1]);
#pragma unroll
        for (int n2 = 0; n2 < 2; ++n2) {
            const int dhb = wn * 32 + n2 * 16 + fq * 4;
            ushort4v o = { f2bf(acc2[m][n2][0] * inv), f2bf(acc2[m][n2][1] * inv),
                           f2bf(acc2[m][n2][2] * inv), f2bf(acc2[m][n2][3] * inv) };
            *(ushort4v*)&qkv[(size_t)(n * 128 + row) * 1536 + h * 64 + dhb] = o;
        }
    }
}

// ---------------- final BN apply (layer 2 BN2 only): fp32 out ----------------
__global__ void bn_apply_final(const u16* __restrict__ y, const float* __restrict__ fin,
                               float* __restrict__ outf) {
    size_t i = ((size_t)blockIdx.x * 256 + threadIdx.x) * 8;
    short8 v = *(const short8*)&y[i];
    int c = (int)(i & 511);
    float o[8];
#pragma unroll
    for (int j = 0; j < 8; ++j)
        o[j] = bf2f((u16)v[j]) * fin[512 + c + j] + fin[c + j];
    float4 a = { o[0], o[1], o[2], o[3] }, b = { o[4], o[5], o[6], o[7] };
    *(float4*)&outf[i] = a;
    *(float4*)&outf[i + 4] = b;
}

// ---------------- launch ----------------
extern "C" void kernel_launch(void* const* d_in, const int* in_sizes, int n_in,
                              void* d_out, int out_size, void* d_ws, size_t ws_size,
                              hipStream_t stream) {
    const float* x  = (const float*)d_in[0];
    const float* Wq = (const float*)d_in[1];  const float* bq = (const float*)d_in[2];
    const float* Wk = (const float*)d_in[3];  const float* bk = (const float*)d_in[4];
    const float* Wv = (const float*)d_in[5];  const float* bv = (const float*)d_in[6];
    const float* Wo = (const float*)d_in[7];  const float* bo = (const float*)d_in[8];
    const float* W1 = (const float*)d_in[9];  const float* b1 = (const float*)d_in[10];
    const float* W2 = (const float*)d_in[11]; const float* b2 = (const float*)d_in[12];
    const float* g1 = (const float*)d_in[13]; const float* be1 = (const float*)d_in[14];
    const float* g2 = (const float*)d_in[15]; const float* be2 = (const float*)d_in[16];

    const int M = 86016;            // 672 * 128
    const int MC = 43008;           // FFN chunk rows (M/2)

    char* ws = (char*)d_ws;
    size_t off = 0;
    auto alloc = [&](size_t bytes) -> void* {
        void* p = ws + off;
        off = (off + bytes + 255) & ~(size_t)255;
        return p;
    };
    u16* scores = (u16*)alloc((size_t)5376 * 16384 * 2);   // 176 MB bf16 (fragment layout)
    u16* hb     = (u16*)alloc((size_t)M * 512 * 2);        //  88 MB residual stream
    u16* qkv    = (u16*)alloc((size_t)M * 1536 * 2);       // 264 MB (qkv; ctx alias; FFN hidden)
    u16* Wqkvt  = (u16*)alloc((size_t)3 * 1536 * 512 * 2);
    u16* Wot    = (u16*)alloc((size_t)3 * 512 * 512 * 2);
    u16* W1t    = (u16*)alloc((size_t)3 * 2048 * 512 * 2);
    u16* W2t    = (u16*)alloc((size_t)3 * 512 * 2048 * 2);
    float* bqkv = (float*)alloc((size_t)3 * 1536 * 4);
    float* raw  = (float*)alloc(2048 * 4);                 // raw1 | raw2
    float* fin1 = (float*)alloc(1024 * 4);                 // t | s  (BN1)
    float* fin2 = (float*)alloc(1024 * 4);                 // t | s  (BN2, persists to next layer)
    float* biasQ = (float*)alloc(1536 * 4);
    float* biasF = (float*)alloc(2048 * 4);
    float* raw1 = raw, *raw2 = raw + 1024;

    if (off > ws_size) return;  // clean diagnostic failure instead of OOB crash

    // prep (batched over layers via gridDim.z)
    wtrans<<<dim3(16, 16, 3), 256, 0, stream>>>(Wq, Wqkvt,                 512, 512,  512 * 512, 1536 * 512);
    wtrans<<<dim3(16, 16, 3), 256, 0, stream>>>(Wk, Wqkvt + 512 * 512,     512, 512,  512 * 512, 1536 * 512);
    wtrans<<<dim3(16, 16, 3), 256, 0, stream>>>(Wv, Wqkvt + 1024 * 512,    512, 512,  512 * 512, 1536 * 512);
    wtrans<<<dim3(16, 16, 3), 256, 0, stream>>>(Wo, Wot,                   512, 512,  512 * 512, 512 * 512);
    wtrans<<<dim3(16, 64, 3), 256, 0, stream>>>(W1, W1t,                   512, 2048, 512 * 2048, 2048 * 512);
    wtrans<<<dim3(64, 16, 3), 256, 0, stream>>>(W2, W2t,                   2048, 512, 2048 * 512, 512 * 2048);
    bias_concat<<<18, 256, 0, stream>>>(bq, bk, bv, bqkv);
    xconvert<<<21504, 256, 0, stream>>>(x, hb);

    for (int e = 0; e < 3; ++e) {
        u16* Wqkv_e = Wqkvt + (size_t)e * 1536 * 512;
        u16* W1_e   = W1t + (size_t)e * 2048 * 512;
        // QKV projection (fold BN2_{e-1} into weights for e>0)
        if (e > 0) {
            bias_fold<<<6, 256, 0, stream>>>(Wqkv_e, bqkv + e * 1536, fin2, biasQ);
            weight_scale<<<384, 256, 0, stream>>>(Wqkv_e, fin2);
        }
        gemm_bt<0><<<dim3(12, 672), 512, 0, stream>>>(hb, 512, Wqkv_e,
                                                      e ? biasQ : bqkv + e * 1536,
                                                      nullptr, qkv, 1536, 512, nullptr, nullptr);
        // attention (ctx written into q-region of qkv)
        if (e == 0)      attn_kernel<0, 1><<<5376, 256, 0, stream>>>(qkv, scores);
        else if (e == 1) attn_kernel<1, 1><<<5376, 256, 0, stream>>>(qkv, scores);
        else             attn_kernel<1, 0><<<5376, 256, 0, stream>>>(qkv, scores);
        // O projection + residual (affine BN2_{e-1} for e>0) -> hb pre-BN1, BN1 stats
        zero_stats2<<<2, 1024, 0, stream>>>(raw);
        if (e == 0)
            gemm_bt<2><<<dim3(4, 672), 512, 0, stream>>>(qkv, 1536, Wot + (size_t)e * 512 * 512,
                                                         bo + e * 512, hb, hb, 512, 512, raw1, nullptr);
        else
            gemm_bt<3><<<dim3(4, 672), 512, 0, stream>>>(qkv, 1536, Wot + (size_t)e * 512 * 512,
                                                         bo + e * 512, hb, hb, 512, 512, raw1, fin2);
        bn_finalize_st<<<2, 256, 0, stream>>>(raw1, g1 + e * 512, be1 + e * 512, fin1, M);
        // FFN1 fold (BN1 into W1), then FFN chunked x2
        bias_fold<<<8, 256, 0, stream>>>(W1_e, b1 + e * 2048, fin1, biasF);
        weight_scale<<<512, 256, 0, stream>>>(W1_e, fin1);
        for (int c = 0; c < 2; ++c) {
            const u16* hc = hb + (size_t)c * MC * 512;
            gemm_bt<1><<<dim3(16, 336), 512, 0, stream>>>(hc, 512, W1_e,
                                                          biasF, nullptr, qkv, 2048, 512, nullptr, nullptr);
            gemm_bt<3><<<dim3(4, 336), 512, 0, stream>>>(qkv, 2048, W2t + (size_t)e * 512 * 2048,
                                                         b2 + e * 512, hc, (u16*)hc, 512, 2048, raw2, fin1);
        }
        bn_finalize_st<<<2, 256, 0, stream>>>(raw2, g2 + e * 512, be2 + e * 512, fin2, M);
        if (e == 2)
            bn_apply_final<<<21504, 256, 0, stream>>>(hb, fin2, (float*)d_out);
    }
    (void)in_sizes; (void)n_in; (void)out_size;
}

// Round 17
// 3237.109 us; speedup vs baseline: 1.1652x; 1.1652x over previous
//
#include <hip/hip_runtime.h>
#include <hip/hip_bf16.h>

// PatchTST encoder: 3 layers of {QKV proj, RealFormer attn, O proj + BN, FFN(GELU) + BN}
// B=32,V=21 -> N=672 seqs; L=128, D=512, H=8, DH=64, F=2048.
// Round 17: revert to r14 (best, 3272us): BN-fold closed after two failures
// (EPI-3 epilogue pushes GEMM over the 64-VGPR granule; pinning spills the K-loop).
// Kept from r15: batched wtrans (18->6 launches), combined stats zeroing.

typedef unsigned short u16;
typedef unsigned int u32;
typedef __attribute__((ext_vector_type(8))) short short8;
typedef __attribute__((ext_vector_type(4))) float floatx4;
typedef __attribute__((ext_vector_type(4))) unsigned short ushort4v;

#define DEV static __device__ __forceinline__

DEV u16 f2bf(float f) {
    union { float f; u32 u; } a; a.f = f;
    u32 r = a.u + 0x7FFF + ((a.u >> 16) & 1);   // RNE
    return (u16)(r >> 16);
}
DEV float bf2f(u16 b) {
    union { u32 u; float f; } a; a.u = ((u32)b) << 16; return a.f;
}

DEV void gload16(const void* g, void* l) {
    __builtin_amdgcn_global_load_lds((const __attribute__((address_space(1))) void*)g,
                                     (__attribute__((address_space(3))) void*)l, 16, 0, 0);
}

// ---------------- weight transpose fp32[K][N] -> bf16[N][K], batched over z ------
__global__ void wtrans(const float* __restrict__ W, u16* __restrict__ out, int K, int N,
                       int inStride, int outStride) {
    W += (size_t)blockIdx.z * inStride;
    out += (size_t)blockIdx.z * outStride;
    __shared__ float tile[32][33];
    const int k0 = blockIdx.x * 32, n0 = blockIdx.y * 32;
    const int tx = threadIdx.x & 31, ty = threadIdx.x >> 5;  // 32x8
#pragma unroll
    for (int j = 0; j < 4; ++j) {
        int r = ty + j * 8;
        tile[r][tx] = W[(size_t)(k0 + r) * N + n0 + tx];
    }
    __syncthreads();
#pragma unroll
    for (int j = 0; j < 4; ++j) {
        int r = ty + j * 8;
        out[(size_t)(n0 + r) * K + k0 + tx] = f2bf(tile[tx][r]);
    }
}

__global__ void bias_concat(const float* __restrict__ bq, const float* __restrict__ bk,
                            const float* __restrict__ bv, float* __restrict__ bqkv) {
    int t = blockIdx.x * 256 + threadIdx.x;
    if (t >= 3 * 1536) return;
    int e = t / 1536, c = t % 1536;
    float v = (c < 512) ? bq[e * 512 + c] : (c < 1024) ? bk[e * 512 + c - 512] : bv[e * 512 + c - 1024];
    bqkv[t] = v;
}

__global__ void xconvert(const float* __restrict__ x, u16* __restrict__ hb) {
    size_t i = ((size_t)blockIdx.x * 256 + threadIdx.x) * 8;
    float4 v0 = *(const float4*)&x[i];
    float4 v1 = *(const float4*)&x[i + 4];
    short8 o;
    o[0] = (short)f2bf(v0.x); o[1] = (short)f2bf(v0.y); o[2] = (short)f2bf(v0.z); o[3] = (short)f2bf(v0.w);
    o[4] = (short)f2bf(v1.x); o[5] = (short)f2bf(v1.y); o[6] = (short)f2bf(v1.z); o[7] = (short)f2bf(v1.w);
    *(short8*)&hb[i] = o;
}

// ---------------- GEMM: C[M,N] = A[M,K](bf16, row-stride lda) @ Bt[N,K]^T + bias ----
// EPI 0: store bf16; EPI 1: gelu -> bf16; EPI 2: + res(bf16) -> bf16 (+BN stats)
// 512 threads = 8 waves (2m x 4n) over a 128x128 tile; per-wave 64x32 output.
// BK=64, two-barrier drain loop (r12-proven structure).
template <int EPI>
__global__ __launch_bounds__(512)
void gemm_bt(const u16* __restrict__ A, int lda, const u16* __restrict__ Bt,
             const float* __restrict__ bias, const u16* __restrict__ res,
             u16* __restrict__ out, int N, int K, float* __restrict__ stats) {
    __shared__ u16 sA[2][4096];   // [k-half][frag rows 128 x 32]
    __shared__ u16 sB[2][4096];
    const int tid = threadIdx.x;
    const int wave = tid >> 6, lane = tid & 63;
    const int wm = wave >> 2, wn = wave & 3;
    const int m0 = blockIdx.y * 128, n0 = blockIdx.x * 128;
    const int fr = lane & 15, fq = lane >> 4;
    const int srow = lane >> 2, scol = (lane & 3) * 8;

    floatx4 acc[4][2] = {};
    const int NT = K >> 6;

    for (int kt = 0; kt < NT; ++kt) {
        __syncthreads();
        {
            const int ra = wave * 16 + srow;
            const size_t arow = (size_t)(m0 + ra) * lda + kt * 64 + scol;
            const size_t brow = (size_t)(n0 + ra) * (size_t)K + kt * 64 + scol;
#pragma unroll
            for (int kk = 0; kk < 2; ++kk) {
                gload16(A + arow + kk * 32, &sA[kk][wave * 512]);
                gload16(Bt + brow + kk * 32, &sB[kk][wave * 512]);
            }
        }
        __syncthreads();
#pragma unroll
        for (int kk = 0; kk < 2; ++kk) {
            short8 af[4], bfr[2];
#pragma unroll
            for (int m = 0; m < 4; ++m)
                af[m] = *(const short8*)&sA[kk][(wm * 64 + m * 16 + fr) * 32 + fq * 8];
#pragma unroll
            for (int nn = 0; nn < 2; ++nn)
                bfr[nn] = *(const short8*)&sB[kk][(wn * 32 + nn * 16 + fr) * 32 + fq * 8];
#pragma unroll
            for (int m = 0; m < 4; ++m)
#pragma unroll
                for (int nn = 0; nn < 2; ++nn)
                    acc[m][nn] = __builtin_amdgcn_mfma_f32_16x16x32_bf16(af[m], bfr[nn], acc[m][nn], 0, 0, 0);
        }
    }

    // epilogue: C col = lane&15, row = (lane>>4)*4 + reg
    float ssum[2] = { 0.f, 0.f }, sqsum[2] = { 0.f, 0.f };
#pragma unroll
    for (int nn = 0; nn < 2; ++nn) {
        int col = n0 + wn * 32 + nn * 16 + fr;
        float bv = bias[col];
#pragma unroll
        for (int m = 0; m < 4; ++m) {
            int rowb = m0 + wm * 64 + m * 16 + fq * 4;
#pragma unroll
            for (int r = 0; r < 4; ++r) {
                size_t idx = (size_t)(rowb + r) * N + col;
                float v = acc[m][nn][r] + bv;
                if (EPI == 2) {
                    v += bf2f(res[idx]);
                    ssum[nn] += v;
                    sqsum[nn] += v * v;
                } else if (EPI == 1) {
                    v = 0.5f * v * (1.f + erff(v * 0.70710678118f));
                }
                out[idx] = f2bf(v);
            }
        }
    }
    if (EPI == 2) {
#pragma unroll
        for (int nn = 0; nn < 2; ++nn) {
            float s = ssum[nn], q = sqsum[nn];
            s += __shfl_xor(s, 16); s += __shfl_xor(s, 32);
            q += __shfl_xor(q, 16); q += __shfl_xor(q, 32);
            if (fq == 0) {
                int col = n0 + wn * 32 + nn * 16 + fr;
                atomicAdd(&stats[col], s);
                atomicAdd(&stats[512 + col], q);
            }
        }
    }
}

// ---------------- fused attention per (n,h) — r14 version (proven 208us) ----------
// Operand-swapped: thread holds, per m, ONE q-row = wm*64+m*16+fr with 16
// k-values at wn*64+nn*16+fq*4+r. Scores in per-thread fragment layout.
template <int HAS_PREV, int STORE_S>
__global__ __launch_bounds__(256)
void attn_kernel(u16* __restrict__ qkv, u16* __restrict__ scores) {
    const int bid = blockIdx.x;           // n*8 + h
    const int n = bid >> 3, h = bid & 7;
    const int tid = threadIdx.x, wave = tid >> 6, lane = tid & 63;
    const int wm = wave >> 1, wn = wave & 1;
    const int fr = lane & 15, fq = lane >> 4;

    __shared__ __align__(16) u16 uni[128 * 136];   // q/k tiles first, then sP [128][136]
    __shared__ __align__(16) u16 sV[64 * 136];     // V^T [64][136]
    __shared__ float sRed[128 * 2];

    u16 (*sQK)[128 * 32] = (u16(*)[128 * 32])uni;  // tiles: q.k0, q.k1, k.k0, k.k1

    {   // stage q,k tiles (global_load_lds), each wave owns one [128][32] tile
        const int t_ = wave;
        const int qk = t_ >> 1, kh = t_ & 1;
        const u16* base = qkv + (size_t)n * 128 * 1536 + qk * 512 + h * 64 + kh * 32 + (lane & 3) * 8;
        u16* dst = &sQK[t_][0];
        const int rr = lane >> 2;
#pragma unroll
        for (int c = 0; c < 8; ++c)
            gload16(base + (size_t)(c * 16 + rr) * 1536, dst + c * 512);
    }
    {   // stage V transposed: sV[dh][m]; global side vectorized (short8)
        const int mrow = tid >> 1;
        const int dh0 = (tid & 1) * 32;
        const u16* vsrc = qkv + (size_t)(n * 128 + mrow) * 1536 + 1024 + h * 64 + dh0;
#pragma unroll
        for (int j = 0; j < 4; ++j) {
            short8 vv = *(const short8*)&vsrc[j * 8];
#pragma unroll
            for (int e2 = 0; e2 < 8; ++e2)
                sV[(dh0 + j * 8 + e2) * 136 + mrow] = (u16)vv[e2];
        }
    }
    __syncthreads();  // [A]

    // QK^T swapped: acc[m][nn] -> S[q-row = wm*64+m*16+fr][k = wn*64+nn*16+fq*4+r]
    floatx4 acc[4][4] = {};
#pragma unroll
    for (int kh = 0; kh < 2; ++kh) {
        short8 a[4], b[4];
#pragma unroll
        for (int m = 0; m < 4; ++m)
            a[m] = *(const short8*)&sQK[kh][(wm * 64 + m * 16 + fr) * 32 + fq * 8];
#pragma unroll
        for (int nn = 0; nn < 4; ++nn)
            b[nn] = *(const short8*)&sQK[2 + kh][(wn * 64 + nn * 16 + fr) * 32 + fq * 8];
#pragma unroll
        for (int m = 0; m < 4; ++m)
#pragma unroll
            for (int nn = 0; nn < 4; ++nn)
                acc[m][nn] = __builtin_amdgcn_mfma_f32_16x16x32_bf16(b[nn], a[m], acc[m][nn], 0, 0, 0);
    }

    // scale, + prev scores, store new scores — fragment layout, short8 I/O
    const size_t tbase = ((size_t)bid * 256 + tid) * 64;
#pragma unroll
    for (int m = 0; m < 4; ++m) {
        short8 lo, hi;
        if (HAS_PREV) {
            lo = *(const short8*)&scores[tbase + m * 16];
            hi = *(const short8*)&scores[tbase + m * 16 + 8];
        }
#pragma unroll
        for (int nn = 0; nn < 4; ++nn)
#pragma unroll
            for (int r = 0; r < 4; ++r) {
                const int e = nn * 4 + r;
                float v = acc[m][nn][r] * 0.125f;
                if (HAS_PREV) v += bf2f((u16)(e < 8 ? lo[e] : hi[e - 8]));
                acc[m][nn][r] = v;
            }
        if (STORE_S) {
            short8 slo, shi;
#pragma unroll
            for (int nn = 0; nn < 4; ++nn)
#pragma unroll
                for (int r = 0; r < 4; ++r) {
                    const int e = nn * 4 + r;
                    u16 bv = f2bf(acc[m][nn][r]);
                    if (e < 8) slo[e] = (short)bv; else shi[e - 8] = (short)bv;
                }
            *(short8*)&scores[tbase + m * 16] = slo;
            *(short8*)&scores[tbase + m * 16 + 8] = shi;
        }
    }

    // row max: in-thread over 16 k-values, shfl over fq (16,32), 2-way wn via LDS
#pragma unroll
    for (int m = 0; m < 4; ++m) {
        const int row = wm * 64 + m * 16 + fr;
        float mx = acc[m][0][0];
#pragma unroll
        for (int nn = 0; nn < 4; ++nn)
#pragma unroll
            for (int r = 0; r < 4; ++r) mx = fmaxf(mx, acc[m][nn][r]);
        mx = fmaxf(mx, __shfl_xor(mx, 16));
        mx = fmaxf(mx, __shfl_xor(mx, 32));
        if (fq == 0) sRed[row * 2 + wn] = mx;
    }
    __syncthreads();  // [B] sQK reads done; max partials ready

    float rmax[4];
#pragma unroll
    for (int m = 0; m < 4; ++m) {
        const int row = wm * 64 + m * 16 + fr;
        rmax[m] = fmaxf(sRed[row * 2], sRed[row * 2 + 1]);
    }
    __syncthreads();  // [C] protect sRed overwrite

    u16* sP = uni;
#pragma unroll
    for (int m = 0; m < 4; ++m) {
        const int row = wm * 64 + m * 16 + fr;
        float sm = 0.f;
#pragma unroll
        for (int nn = 0; nn < 4; ++nn) {
#pragma unroll
            for (int r = 0; r < 4; ++r) {
                float p = __expf(acc[m][nn][r] - rmax[m]);
                acc[m][nn][r] = p;
                sm += p;
            }
        }
        sm += __shfl_xor(sm, 16);
        sm += __shfl_xor(sm, 32);
        if (fq == 0) sRed[row * 2 + wn] = sm;
#pragma unroll
        for (int nn = 0; nn < 4; ++nn) {
            ushort4v pv = { f2bf(acc[m][nn][0]), f2bf(acc[m][nn][1]),
                            f2bf(acc[m][nn][2]), f2bf(acc[m][nn][3]) };
            *(ushort4v*)&sP[row * 136 + wn * 64 + nn * 16 + fq * 4] = pv;
        }
    }
    __syncthreads();  // [D] P + sums ready

    // P @ V swapped: acc2[m][n2] -> ctx[q = wm*64+m*16+fr][dh = wn*32+n2*16+fq*4+r]
    floatx4 acc2[4][2] = {};
#pragma unroll
    for (int k0 = 0; k0 < 128; k0 += 32) {
        short8 a[4], b[2];
#pragma unroll
        for (int m = 0; m < 4; ++m)
            a[m] = *(const short8*)&sP[(wm * 64 + m * 16 + fr) * 136 + k0 + fq * 8];
#pragma unroll
        for (int n2 = 0; n2 < 2; ++n2)
            b[n2] = *(const short8*)&sV[(wn * 32 + n2 * 16 + fr) * 136 + k0 + fq * 8];
#pragma unroll
        for (int m = 0; m < 4; ++m)
#pragma unroll
            for (int n2 = 0; n2 < 2; ++n2)
                acc2[m][n2] = __builtin_amdgcn_mfma_f32_16x16x32_bf16(b[n2], a[m], acc2[m][n2], 0, 0, 0);
    }

#pragma unroll
    for (int m = 0; m < 4; ++m) {
        const int row = wm * 64 + m * 16 + fr;
        const float inv = 1.f / (sRed[row * 2] + sRed[row * 2 + 1]);
#pragma unroll
        for (int n2 = 0; n2 < 2; ++n2) {
            const int dhb = wn * 32 + n2 * 16 + fq * 4;
            ushort4v o = { f2bf(acc2[m][n2][0] * inv), f2bf(acc2[m][n2][1] * inv),
                           f2bf(acc2[m][n2][2] * inv), f2bf(acc2[m][n2][3] * inv) };
            *(ushort4v*)&qkv[(size_t)(n * 128 + row) * 1536 + h * 64 + dhb] = o;
        }
    }
}

// ---------------- batch norm (stats fused into GEMM epilogues) ----------------
__global__ void zero_stats2(float* raw) { raw[blockIdx.x * 1024 + threadIdx.x] = 0.f; }

__global__ void bn_finalize(float* stats, int M) {
    int c = blockIdx.x * 256 + threadIdx.x;
    if (c >= 512) return;
    float mean = stats[c] / M;
    float var = stats[512 + c] / M - mean * mean;
    stats[c] = mean;
    stats[512 + c] = rsqrtf(var + 1e-5f);
}

// FINAL=0: write bf16 in place; FINAL=1: write fp32 to outf
template <int FINAL>
__global__ void bn_apply(const u16* __restrict__ y, const float* __restrict__ stats,
                         const float* __restrict__ gamma, const float* __restrict__ beta,
                         u16* __restrict__ outb, float* __restrict__ outf) {
    size_t i = ((size_t)blockIdx.x * 256 + threadIdx.x) * 8;
    short8 v = *(const short8*)&y[i];
    int c = (int)(i & 511);
    float o[8];
#pragma unroll
    for (int j = 0; j < 8; ++j) {
        float f = bf2f((u16)v[j]);
        o[j] = (f - stats[c + j]) * stats[512 + c + j] * gamma[c + j] + beta[c + j];
    }
    if (FINAL) {
        float4 a = { o[0], o[1], o[2], o[3] }, b = { o[4], o[5], o[6], o[7] };
        *(float4*)&outf[i] = a;
        *(float4*)&outf[i + 4] = b;
    } else {
        short8 ob;
#pragma unroll
        for (int j = 0; j < 8; ++j) ob[j] = (short)f2bf(o[j]);
        *(short8*)&outb[i] = ob;
    }
}

// ---------------- launch ----------------
extern "C" void kernel_launch(void* const* d_in, const int* in_sizes, int n_in,
                              void* d_out, int out_size, void* d_ws, size_t ws_size,
                              hipStream_t stream) {
    const float* x  = (const float*)d_in[0];
    const float* Wq = (const float*)d_in[1];  const float* bq = (const float*)d_in[2];
    const float* Wk = (const float*)d_in[3];  const float* bk = (const float*)d_in[4];
    const float* Wv = (const float*)d_in[5];  const float* bv = (const float*)d_in[6];
    const float* Wo = (const float*)d_in[7];  const float* bo = (const float*)d_in[8];
    const float* W1 = (const float*)d_in[9];  const float* b1 = (const float*)d_in[10];
    const float* W2 = (const float*)d_in[11]; const float* b2 = (const float*)d_in[12];
    const float* g1 = (const float*)d_in[13]; const float* be1 = (const float*)d_in[14];
    const float* g2 = (const float*)d_in[15]; const float* be2 = (const float*)d_in[16];

    const int M = 86016;            // 672 * 128
    const int MC = 43008;           // FFN chunk rows (M/2)

    char* ws = (char*)d_ws;
    size_t off = 0;
    auto alloc = [&](size_t bytes) -> void* {
        void* p = ws + off;
        off = (off + bytes + 255) & ~(size_t)255;
        return p;
    };
    u16* scores = (u16*)alloc((size_t)5376 * 16384 * 2);   // 176 MB bf16 (fragment layout)
    u16* hb     = (u16*)alloc((size_t)M * 512 * 2);        //  88 MB residual stream
    u16* qkv    = (u16*)alloc((size_t)M * 1536 * 2);       // 264 MB (qkv; ctx alias; FFN hidden)
    u16* Wqkvt  = (u16*)alloc((size_t)3 * 1536 * 512 * 2);
    u16* Wot    = (u16*)alloc((size_t)3 * 512 * 512 * 2);
    u16* W1t    = (u16*)alloc((size_t)3 * 2048 * 512 * 2);
    u16* W2t    = (u16*)alloc((size_t)3 * 512 * 2048 * 2);
    float* bqkv = (float*)alloc((size_t)3 * 1536 * 4);
    float* raw  = (float*)alloc(2048 * 4);                 // raw1 | raw2
    float* raw1 = raw, *raw2 = raw + 1024;

    if (off > ws_size) return;  // clean diagnostic failure instead of OOB crash

    // prep (batched over layers via gridDim.z)
    wtrans<<<dim3(16, 16, 3), 256, 0, stream>>>(Wq, Wqkvt,              512, 512,  512 * 512, 1536 * 512);
    wtrans<<<dim3(16, 16, 3), 256, 0, stream>>>(Wk, Wqkvt + 512 * 512,  512, 512,  512 * 512, 1536 * 512);
    wtrans<<<dim3(16, 16, 3), 256, 0, stream>>>(Wv, Wqkvt + 1024 * 512, 512, 512,  512 * 512, 1536 * 512);
    wtrans<<<dim3(16, 16, 3), 256, 0, stream>>>(Wo, Wot,                512, 512,  512 * 512, 512 * 512);
    wtrans<<<dim3(16, 64, 3), 256, 0, stream>>>(W1, W1t,                512, 2048, 512 * 2048, 2048 * 512);
    wtrans<<<dim3(64, 16, 3), 256, 0, stream>>>(W2, W2t,                2048, 512, 2048 * 512, 512 * 2048);
    bias_concat<<<18, 256, 0, stream>>>(bq, bk, bv, bqkv);
    xconvert<<<21504, 256, 0, stream>>>(x, hb);

    for (int e = 0; e < 3; ++e) {
        // QKV projection
        gemm_bt<0><<<dim3(12, 672), 512, 0, stream>>>(hb, 512, Wqkvt + (size_t)e * 1536 * 512,
                                                      bqkv + e * 1536, nullptr, qkv, 1536, 512, nullptr);
        // attention (ctx written into q-region of qkv)
        if (e == 0)      attn_kernel<0, 1><<<5376, 256, 0, stream>>>(qkv, scores);
        else if (e == 1) attn_kernel<1, 1><<<5376, 256, 0, stream>>>(qkv, scores);
        else             attn_kernel<1, 0><<<5376, 256, 0, stream>>>(qkv, scores);
        // zero BOTH stat regions once per layer
        zero_stats2<<<2, 1024, 0, stream>>>(raw);
        // O projection + residual -> hb (bf16, in place), BN1 stats fused
        gemm_bt<2><<<dim3(4, 672), 512, 0, stream>>>(qkv, 1536, Wot + (size_t)e * 512 * 512,
                                                     bo + e * 512, hb, hb, 512, 512, raw1);
        bn_finalize<<<2, 256, 0, stream>>>(raw1, M);
        bn_apply<0><<<21504, 256, 0, stream>>>(hb, raw1, g1 + e * 512, be1 + e * 512, hb, nullptr);
        // FFN, chunked x2 (hidden lives in qkv region, dead here), BN2 stats fused
        for (int c = 0; c < 2; ++c) {
            const u16* hc = hb + (size_t)c * MC * 512;
            gemm_bt<1><<<dim3(16, 336), 512, 0, stream>>>(hc, 512, W1t + (size_t)e * 2048 * 512,
                                                          b1 + e * 2048, nullptr, qkv, 2048, 512, nullptr);
            gemm_bt<2><<<dim3(4, 336), 512, 0, stream>>>(qkv, 2048, W2t + (size_t)e * 512 * 2048,
                                                         b2 + e * 512, hc, (u16*)hc, 512, 2048, raw2);
        }
        bn_finalize<<<2, 256, 0, stream>>>(raw2, M);
        if (e < 2)
            bn_apply<0><<<21504, 256, 0, stream>>>(hb, raw2, g2 + e * 512, be2 + e * 512, hb, nullptr);
        else
            bn_apply<1><<<21504, 256, 0, stream>>>(hb, raw2, g2 + e * 512, be2 + e * 512, nullptr, (float*)d_out);
    }
    (void)in_sizes; (void)n_in; (void)out_size;
}

// Round 18
// 3218.909 us; speedup vs baseline: 1.1718x; 1.0057x over previous
//
#include <hip/hip_runtime.h>
#include <hip/hip_bf16.h>

// PatchTST encoder: 3 layers of {QKV proj, RealFormer attn, O proj + BN, FFN(GELU) + BN}
// B=32,V=21 -> N=672 seqs; L=128, D=512, H=8, DH=64, F=2048.
// Round 18: r17 base (3237us best) + attn micro-opts:
//  (1) scores prefetch at kernel entry (T14 issue-early; loads hidden under
//      staging + QK^T MFMA instead of exposed serially before softmax),
//  (2) barrier [C] removed via separate sSum buffer (+1KB LDS, 3-block cap kept).

typedef unsigned short u16;
typedef unsigned int u32;
typedef __attribute__((ext_vector_type(8))) short short8;
typedef __attribute__((ext_vector_type(4))) float floatx4;
typedef __attribute__((ext_vector_type(4))) unsigned short ushort4v;

#define DEV static __device__ __forceinline__

DEV u16 f2bf(float f) {
    union { float f; u32 u; } a; a.f = f;
    u32 r = a.u + 0x7FFF + ((a.u >> 16) & 1);   // RNE
    return (u16)(r >> 16);
}
DEV float bf2f(u16 b) {
    union { u32 u; float f; } a; a.u = ((u32)b) << 16; return a.f;
}

DEV void gload16(const void* g, void* l) {
    __builtin_amdgcn_global_load_lds((const __attribute__((address_space(1))) void*)g,
                                     (__attribute__((address_space(3))) void*)l, 16, 0, 0);
}

// ---------------- weight transpose fp32[K][N] -> bf16[N][K], batched over z ------
__global__ void wtrans(const float* __restrict__ W, u16* __restrict__ out, int K, int N,
                       int inStride, int outStride) {
    W += (size_t)blockIdx.z * inStride;
    out += (size_t)blockIdx.z * outStride;
    __shared__ float tile[32][33];
    const int k0 = blockIdx.x * 32, n0 = blockIdx.y * 32;
    const int tx = threadIdx.x & 31, ty = threadIdx.x >> 5;  // 32x8
#pragma unroll
    for (int j = 0; j < 4; ++j) {
        int r = ty + j * 8;
        tile[r][tx] = W[(size_t)(k0 + r) * N + n0 + tx];
    }
    __syncthreads();
#pragma unroll
    for (int j = 0; j < 4; ++j) {
        int r = ty + j * 8;
        out[(size_t)(n0 + r) * K + k0 + tx] = f2bf(tile[tx][r]);
    }
}

__global__ void bias_concat(const float* __restrict__ bq, const float* __restrict__ bk,
                            const float* __restrict__ bv, float* __restrict__ bqkv) {
    int t = blockIdx.x * 256 + threadIdx.x;
    if (t >= 3 * 1536) return;
    int e = t / 1536, c = t % 1536;
    float v = (c < 512) ? bq[e * 512 + c] : (c < 1024) ? bk[e * 512 + c - 512] : bv[e * 512 + c - 1024];
    bqkv[t] = v;
}

__global__ void xconvert(const float* __restrict__ x, u16* __restrict__ hb) {
    size_t i = ((size_t)blockIdx.x * 256 + threadIdx.x) * 8;
    float4 v0 = *(const float4*)&x[i];
    float4 v1 = *(const float4*)&x[i + 4];
    short8 o;
    o[0] = (short)f2bf(v0.x); o[1] = (short)f2bf(v0.y); o[2] = (short)f2bf(v0.z); o[3] = (short)f2bf(v0.w);
    o[4] = (short)f2bf(v1.x); o[5] = (short)f2bf(v1.y); o[6] = (short)f2bf(v1.z); o[7] = (short)f2bf(v1.w);
    *(short8*)&hb[i] = o;
}

// ---------------- GEMM: C[M,N] = A[M,K](bf16, row-stride lda) @ Bt[N,K]^T + bias ----
// EPI 0: store bf16; EPI 1: gelu -> bf16; EPI 2: + res(bf16) -> bf16 (+BN stats)
// 512 threads = 8 waves (2m x 4n) over a 128x128 tile; per-wave 64x32 output.
// BK=64, two-barrier drain loop (r12-proven structure).
template <int EPI>
__global__ __launch_bounds__(512)
void gemm_bt(const u16* __restrict__ A, int lda, const u16* __restrict__ Bt,
             const float* __restrict__ bias, const u16* __restrict__ res,
             u16* __restrict__ out, int N, int K, float* __restrict__ stats) {
    __shared__ u16 sA[2][4096];   // [k-half][frag rows 128 x 32]
    __shared__ u16 sB[2][4096];
    const int tid = threadIdx.x;
    const int wave = tid >> 6, lane = tid & 63;
    const int wm = wave >> 2, wn = wave & 3;
    const int m0 = blockIdx.y * 128, n0 = blockIdx.x * 128;
    const int fr = lane & 15, fq = lane >> 4;
    const int srow = lane >> 2, scol = (lane & 3) * 8;

    floatx4 acc[4][2] = {};
    const int NT = K >> 6;

    for (int kt = 0; kt < NT; ++kt) {
        __syncthreads();
        {
            const int ra = wave * 16 + srow;
            const size_t arow = (size_t)(m0 + ra) * lda + kt * 64 + scol;
            const size_t brow = (size_t)(n0 + ra) * (size_t)K + kt * 64 + scol;
#pragma unroll
            for (int kk = 0; kk < 2; ++kk) {
                gload16(A + arow + kk * 32, &sA[kk][wave * 512]);
                gload16(Bt + brow + kk * 32, &sB[kk][wave * 512]);
            }
        }
        __syncthreads();
#pragma unroll
        for (int kk = 0; kk < 2; ++kk) {
            short8 af[4], bfr[2];
#pragma unroll
            for (int m = 0; m < 4; ++m)
                af[m] = *(const short8*)&sA[kk][(wm * 64 + m * 16 + fr) * 32 + fq * 8];
#pragma unroll
            for (int nn = 0; nn < 2; ++nn)
                bfr[nn] = *(const short8*)&sB[kk][(wn * 32 + nn * 16 + fr) * 32 + fq * 8];
#pragma unroll
            for (int m = 0; m < 4; ++m)
#pragma unroll
                for (int nn = 0; nn < 2; ++nn)
                    acc[m][nn] = __builtin_amdgcn_mfma_f32_16x16x32_bf16(af[m], bfr[nn], acc[m][nn], 0, 0, 0);
        }
    }

    // epilogue: C col = lane&15, row = (lane>>4)*4 + reg
    float ssum[2] = { 0.f, 0.f }, sqsum[2] = { 0.f, 0.f };
#pragma unroll
    for (int nn = 0; nn < 2; ++nn) {
        int col = n0 + wn * 32 + nn * 16 + fr;
        float bv = bias[col];
#pragma unroll
        for (int m = 0; m < 4; ++m) {
            int rowb = m0 + wm * 64 + m * 16 + fq * 4;
#pragma unroll
            for (int r = 0; r < 4; ++r) {
                size_t idx = (size_t)(rowb + r) * N + col;
                float v = acc[m][nn][r] + bv;
                if (EPI == 2) {
                    v += bf2f(res[idx]);
                    ssum[nn] += v;
                    sqsum[nn] += v * v;
                } else if (EPI == 1) {
                    v = 0.5f * v * (1.f + erff(v * 0.70710678118f));
                }
                out[idx] = f2bf(v);
            }
        }
    }
    if (EPI == 2) {
#pragma unroll
        for (int nn = 0; nn < 2; ++nn) {
            float s = ssum[nn], q = sqsum[nn];
            s += __shfl_xor(s, 16); s += __shfl_xor(s, 32);
            q += __shfl_xor(q, 16); q += __shfl_xor(q, 32);
            if (fq == 0) {
                int col = n0 + wn * 32 + nn * 16 + fr;
                atomicAdd(&stats[col], s);
                atomicAdd(&stats[512 + col], q);
            }
        }
    }
}

// ---------------- fused attention per (n,h) — r14 + scores prefetch, 3 barriers ----
template <int HAS_PREV, int STORE_S>
__global__ __launch_bounds__(256)
void attn_kernel(u16* __restrict__ qkv, u16* __restrict__ scores) {
    const int bid = blockIdx.x;           // n*8 + h
    const int n = bid >> 3, h = bid & 7;
    const int tid = threadIdx.x, wave = tid >> 6, lane = tid & 63;
    const int wm = wave >> 1, wn = wave & 1;
    const int fr = lane & 15, fq = lane >> 4;

    __shared__ __align__(16) u16 uni[128 * 136];   // q/k tiles first, then sP [128][136]
    __shared__ __align__(16) u16 sV[64 * 136];     // V^T [64][136]
    __shared__ float sRed[128 * 2];                // row max partials
    __shared__ float sSum[128 * 2];                // row sum partials (no [C] barrier)

    u16 (*sQK)[128 * 32] = (u16(*)[128 * 32])uni;  // tiles: q.k0, q.k1, k.k0, k.k1

    // -------- scores prefetch (issue-early; consumed after QK^T) --------
    const size_t tbase = ((size_t)bid * 256 + tid) * 64;
    short8 pf[8];
    if (HAS_PREV) {
#pragma unroll
        for (int m = 0; m < 4; ++m) {
            pf[2 * m]     = *(const short8*)&scores[tbase + m * 16];
            pf[2 * m + 1] = *(const short8*)&scores[tbase + m * 16 + 8];
        }
    }

    {   // stage q,k tiles (global_load_lds), each wave owns one [128][32] tile
        const int t_ = wave;
        const int qk = t_ >> 1, kh = t_ & 1;
        const u16* base = qkv + (size_t)n * 128 * 1536 + qk * 512 + h * 64 + kh * 32 + (lane & 3) * 8;
        u16* dst = &sQK[t_][0];
        const int rr = lane >> 2;
#pragma unroll
        for (int c = 0; c < 8; ++c)
            gload16(base + (size_t)(c * 16 + rr) * 1536, dst + c * 512);
    }
    {   // stage V transposed: sV[dh][m]; global side vectorized (short8)
        const int mrow = tid >> 1;
        const int dh0 = (tid & 1) * 32;
        const u16* vsrc = qkv + (size_t)(n * 128 + mrow) * 1536 + 1024 + h * 64 + dh0;
#pragma unroll
        for (int j = 0; j < 4; ++j) {
            short8 vv = *(const short8*)&vsrc[j * 8];
#pragma unroll
            for (int e2 = 0; e2 < 8; ++e2)
                sV[(dh0 + j * 8 + e2) * 136 + mrow] = (u16)vv[e2];
        }
    }
    __syncthreads();  // [A]

    // QK^T swapped: acc[m][nn] -> S[q-row = wm*64+m*16+fr][k = wn*64+nn*16+fq*4+r]
    floatx4 acc[4][4] = {};
#pragma unroll
    for (int kh = 0; kh < 2; ++kh) {
        short8 a[4], b[4];
#pragma unroll
        for (int m = 0; m < 4; ++m)
            a[m] = *(const short8*)&sQK[kh][(wm * 64 + m * 16 + fr) * 32 + fq * 8];
#pragma unroll
        for (int nn = 0; nn < 4; ++nn)
            b[nn] = *(const short8*)&sQK[2 + kh][(wn * 64 + nn * 16 + fr) * 32 + fq * 8];
#pragma unroll
        for (int m = 0; m < 4; ++m)
#pragma unroll
            for (int nn = 0; nn < 4; ++nn)
                acc[m][nn] = __builtin_amdgcn_mfma_f32_16x16x32_bf16(b[nn], a[m], acc[m][nn], 0, 0, 0);
    }

    // scale, + prefetched prev scores, store new scores
#pragma unroll
    for (int m = 0; m < 4; ++m) {
#pragma unroll
        for (int nn = 0; nn < 4; ++nn)
#pragma unroll
            for (int r = 0; r < 4; ++r) {
                const int e = nn * 4 + r;
                float v = acc[m][nn][r] * 0.125f;
                if (HAS_PREV)
                    v += bf2f((u16)(e < 8 ? pf[2 * m][e] : pf[2 * m + 1][e - 8]));
                acc[m][nn][r] = v;
            }
        if (STORE_S) {
            short8 slo, shi;
#pragma unroll
            for (int nn = 0; nn < 4; ++nn)
#pragma unroll
                for (int r = 0; r < 4; ++r) {
                    const int e = nn * 4 + r;
                    u16 bv = f2bf(acc[m][nn][r]);
                    if (e < 8) slo[e] = (short)bv; else shi[e - 8] = (short)bv;
                }
            *(short8*)&scores[tbase + m * 16] = slo;
            *(short8*)&scores[tbase + m * 16 + 8] = shi;
        }
    }

    // row max: in-thread over 16 k-values, shfl over fq (16,32), 2-way wn via LDS
#pragma unroll
    for (int m = 0; m < 4; ++m) {
        const int row = wm * 64 + m * 16 + fr;
        float mx = acc[m][0][0];
#pragma unroll
        for (int nn = 0; nn < 4; ++nn)
#pragma unroll
            for (int r = 0; r < 4; ++r) mx = fmaxf(mx, acc[m][nn][r]);
        mx = fmaxf(mx, __shfl_xor(mx, 16));
        mx = fmaxf(mx, __shfl_xor(mx, 32));
        if (fq == 0) sRed[row * 2 + wn] = mx;
    }
    __syncthreads();  // [B] sQK reads done; max partials ready

    float rmax[4];
#pragma unroll
    for (int m = 0; m < 4; ++m) {
        const int row = wm * 64 + m * 16 + fr;
        rmax[m] = fmaxf(sRed[row * 2], sRed[row * 2 + 1]);
    }
    // no barrier: sums go to sSum (separate buffer)

    u16* sP = uni;
#pragma unroll
    for (int m = 0; m < 4; ++m) {
        const int row = wm * 64 + m * 16 + fr;
        float sm = 0.f;
#pragma unroll
        for (int nn = 0; nn < 4; ++nn) {
#pragma unroll
            for (int r = 0; r < 4; ++r) {
                float p = __expf(acc[m][nn][r] - rmax[m]);
                acc[m][nn][r] = p;
                sm += p;
            }
        }
        sm += __shfl_xor(sm, 16);
        sm += __shfl_xor(sm, 32);
        if (fq == 0) sSum[row * 2 + wn] = sm;
#pragma unroll
        for (int nn = 0; nn < 4; ++nn) {
            ushort4v pv = { f2bf(acc[m][nn][0]), f2bf(acc[m][nn][1]),
                            f2bf(acc[m][nn][2]), f2bf(acc[m][nn][3]) };
            *(ushort4v*)&sP[row * 136 + wn * 64 + nn * 16 + fq * 4] = pv;
        }
    }
    __syncthreads();  // [D] sP + sums ready

    // P @ V swapped: acc2[m][n2] -> ctx[q = wm*64+m*16+fr][dh = wn*32+n2*16+fq*4+r]
    floatx4 acc2[4][2] = {};
#pragma unroll
    for (int k0 = 0; k0 < 128; k0 += 32) {
        short8 a[4], b[2];
#pragma unroll
        for (int m = 0; m < 4; ++m)
            a[m] = *(const short8*)&sP[(wm * 64 + m * 16 + fr) * 136 + k0 + fq * 8];
#pragma unroll
        for (int n2 = 0; n2 < 2; ++n2)
            b[n2] = *(const short8*)&sV[(wn * 32 + n2 * 16 + fr) * 136 + k0 + fq * 8];
#pragma unroll
        for (int m = 0; m < 4; ++m)
#pragma unroll
            for (int n2 = 0; n2 < 2; ++n2)
                acc2[m][n2] = __builtin_amdgcn_mfma_f32_16x16x32_bf16(b[n2], a[m], acc2[m][n2], 0, 0, 0);
    }

#pragma unroll
    for (int m = 0; m < 4; ++m) {
        const int row = wm * 64 + m * 16 + fr;
        const float inv = 1.f / (sSum[row * 2] + sSum[row * 2 + 1]);
#pragma unroll
        for (int n2 = 0; n2 < 2; ++n2) {
            const int dhb = wn * 32 + n2 * 16 + fq * 4;
            ushort4v o = { f2bf(acc2[m][n2][0] * inv), f2bf(acc2[m][n2][1] * inv),
                           f2bf(acc2[m][n2][2] * inv), f2bf(acc2[m][n2][3] * inv) };
            *(ushort4v*)&qkv[(size_t)(n * 128 + row) * 1536 + h * 64 + dhb] = o;
        }
    }
}

// ---------------- batch norm (stats fused into GEMM epilogues) ----------------
__global__ void zero_stats2(float* raw) { raw[blockIdx.x * 1024 + threadIdx.x] = 0.f; }

__global__ void bn_finalize(float* stats, int M) {
    int c = blockIdx.x * 256 + threadIdx.x;
    if (c >= 512) return;
    float mean = stats[c] / M;
    float var = stats[512 + c] / M - mean * mean;
    stats[c] = mean;
    stats[512 + c] = rsqrtf(var + 1e-5f);
}

// FINAL=0: write bf16 in place; FINAL=1: write fp32 to outf
template <int FINAL>
__global__ void bn_apply(const u16* __restrict__ y, const float* __restrict__ stats,
                         const float* __restrict__ gamma, const float* __restrict__ beta,
                         u16* __restrict__ outb, float* __restrict__ outf) {
    size_t i = ((size_t)blockIdx.x * 256 + threadIdx.x) * 8;
    short8 v = *(const short8*)&y[i];
    int c = (int)(i & 511);
    float o[8];
#pragma unroll
    for (int j = 0; j < 8; ++j) {
        float f = bf2f((u16)v[j]);
        o[j] = (f - stats[c + j]) * stats[512 + c + j] * gamma[c + j] + beta[c + j];
    }
    if (FINAL) {
        float4 a = { o[0], o[1], o[2], o[3] }, b = { o[4], o[5], o[6], o[7] };
        *(float4*)&outf[i] = a;
        *(float4*)&outf[i + 4] = b;
    } else {
        short8 ob;
#pragma unroll
        for (int j = 0; j < 8; ++j) ob[j] = (short)f2bf(o[j]);
        *(short8*)&outb[i] = ob;
    }
}

// ---------------- launch ----------------
extern "C" void kernel_launch(void* const* d_in, const int* in_sizes, int n_in,
                              void* d_out, int out_size, void* d_ws, size_t ws_size,
                              hipStream_t stream) {
    const float* x  = (const float*)d_in[0];
    const float* Wq = (const float*)d_in[1];  const float* bq = (const float*)d_in[2];
    const float* Wk = (const float*)d_in[3];  const float* bk = (const float*)d_in[4];
    const float* Wv = (const float*)d_in[5];  const float* bv = (const float*)d_in[6];
    const float* Wo = (const float*)d_in[7];  const float* bo = (const float*)d_in[8];
    const float* W1 = (const float*)d_in[9];  const float* b1 = (const float*)d_in[10];
    const float* W2 = (const float*)d_in[11]; const float* b2 = (const float*)d_in[12];
    const float* g1 = (const float*)d_in[13]; const float* be1 = (const float*)d_in[14];
    const float* g2 = (const float*)d_in[15]; const float* be2 = (const float*)d_in[16];

    const int M = 86016;            // 672 * 128
    const int MC = 43008;           // FFN chunk rows (M/2)

    char* ws = (char*)d_ws;
    size_t off = 0;
    auto alloc = [&](size_t bytes) -> void* {
        void* p = ws + off;
        off = (off + bytes + 255) & ~(size_t)255;
        return p;
    };
    u16* scores = (u16*)alloc((size_t)5376 * 16384 * 2);   // 176 MB bf16 (fragment layout)
    u16* hb     = (u16*)alloc((size_t)M * 512 * 2);        //  88 MB residual stream
    u16* qkv    = (u16*)alloc((size_t)M * 1536 * 2);       // 264 MB (qkv; ctx alias; FFN hidden)
    u16* Wqkvt  = (u16*)alloc((size_t)3 * 1536 * 512 * 2);
    u16* Wot    = (u16*)alloc((size_t)3 * 512 * 512 * 2);
    u16* W1t    = (u16*)alloc((size_t)3 * 2048 * 512 * 2);
    u16* W2t    = (u16*)alloc((size_t)3 * 512 * 2048 * 2);
    float* bqkv = (float*)alloc((size_t)3 * 1536 * 4);
    float* raw  = (float*)alloc(2048 * 4);                 // raw1 | raw2
    float* raw1 = raw, *raw2 = raw + 1024;

    if (off > ws_size) return;  // clean diagnostic failure instead of OOB crash

    // prep (batched over layers via gridDim.z)
    wtrans<<<dim3(16, 16, 3), 256, 0, stream>>>(Wq, Wqkvt,              512, 512,  512 * 512, 1536 * 512);
    wtrans<<<dim3(16, 16, 3), 256, 0, stream>>>(Wk, Wqkvt + 512 * 512,  512, 512,  512 * 512, 1536 * 512);
    wtrans<<<dim3(16, 16, 3), 256, 0, stream>>>(Wv, Wqkvt + 1024 * 512, 512, 512,  512 * 512, 1536 * 512);
    wtrans<<<dim3(16, 16, 3), 256, 0, stream>>>(Wo, Wot,                512, 512,  512 * 512, 512 * 512);
    wtrans<<<dim3(16, 64, 3), 256, 0, stream>>>(W1, W1t,                512, 2048, 512 * 2048, 2048 * 512);
    wtrans<<<dim3(64, 16, 3), 256, 0, stream>>>(W2, W2t,                2048, 512, 2048 * 512, 512 * 2048);
    bias_concat<<<18, 256, 0, stream>>>(bq, bk, bv, bqkv);
    xconvert<<<21504, 256, 0, stream>>>(x, hb);

    for (int e = 0; e < 3; ++e) {
        // QKV projection
        gemm_bt<0><<<dim3(12, 672), 512, 0, stream>>>(hb, 512, Wqkvt + (size_t)e * 1536 * 512,
                                                      bqkv + e * 1536, nullptr, qkv, 1536, 512, nullptr);
        // attention (ctx written into q-region of qkv)
        if (e == 0)      attn_kernel<0, 1><<<5376, 256, 0, stream>>>(qkv, scores);
        else if (e == 1) attn_kernel<1, 1><<<5376, 256, 0, stream>>>(qkv, scores);
        else             attn_kernel<1, 0><<<5376, 256, 0, stream>>>(qkv, scores);
        // zero BOTH stat regions once per layer
        zero_stats2<<<2, 1024, 0, stream>>>(raw);
        // O projection + residual -> hb (bf16, in place), BN1 stats fused
        gemm_bt<2><<<dim3(4, 672), 512, 0, stream>>>(qkv, 1536, Wot + (size_t)e * 512 * 512,
                                                     bo + e * 512, hb, hb, 512, 512, raw1);
        bn_finalize<<<2, 256, 0, stream>>>(raw1, M);
        bn_apply<0><<<21504, 256, 0, stream>>>(hb, raw1, g1 + e * 512, be1 + e * 512, hb, nullptr);
        // FFN, chunked x2 (hidden lives in qkv region, dead here), BN2 stats fused
        for (int c = 0; c < 2; ++c) {
            const u16* hc = hb + (size_t)c * MC * 512;
            gemm_bt<1><<<dim3(16, 336), 512, 0, stream>>>(hc, 512, W1t + (size_t)e * 2048 * 512,
                                                          b1 + e * 2048, nullptr, qkv, 2048, 512, nullptr);
            gemm_bt<2><<<dim3(4, 336), 512, 0, stream>>>(qkv, 2048, W2t + (size_t)e * 512 * 2048,
                                                         b2 + e * 512, hc, (u16*)hc, 512, 2048, raw2);
        }
        bn_finalize<<<2, 256, 0, stream>>>(raw2, M);
        if (e < 2)
            bn_apply<0><<<21504, 256, 0, stream>>>(hb, raw2, g2 + e * 512, be2 + e * 512, hb, nullptr);
        else
            bn_apply<1><<<21504, 256, 0, stream>>>(hb, raw2, g2 + e * 512, be2 + e * 512, nullptr, (float*)d_out);
    }
    (void)in_sizes; (void)n_in; (void)out_size;
}